// Round 9
// baseline (277.804 us; speedup 1.0000x reference)
//
#include <hip/hip_runtime.h>

typedef float f32x4 __attribute__((ext_vector_type(4)));
typedef float f32x16v __attribute__((ext_vector_type(16)));
typedef __bf16 bf16x4 __attribute__((ext_vector_type(4)));
typedef __bf16 bf16x8 __attribute__((ext_vector_type(8)));

union U4B8 { uint4 u; bf16x8 b; };

// ws layout (bf16 elements): b2p[9216] @0, b3p[36864] @9216, c1p[1024] @46080
#define B2P_OFF 0
#define B3P_OFF 9216
#define C1P_OFF 46080

// ------------------------------------------------------------- pack_weights
// b2p frag f=t*2+p: lane l, j: oc=l&31, ic=(l>>5)*8+j              (32x32x16)
// b3p frag f=t*8+nt*2+p: lane l, j: oc=nt*16+(l&15), ic=(l>>4)*8+j (16x16x32)
// c1p frag f in {Bh,Bl}: oc=l&15, k=(l>>4)*8+j, k = kx*9+ky*3+ic (<27), else 0
__global__ __launch_bounds__(256) void pack_weights(
    const float* __restrict__ w1, const float* __restrict__ w2,
    const float* __restrict__ w3, __bf16* __restrict__ wsb) {
  int i = blockIdx.x * 256 + threadIdx.x;
  if (i < 9216) {
    int f = i >> 9, r = i & 511;
    int l = r >> 3, j = r & 7;
    int t = f >> 1, p = f & 1;
    int ky = t / 3, kx = t % 3;
    int oc = l & 31, ic = ((l >> 5) << 3) + j;
    float v = w2[oc * 144 + ic * 9 + ky * 3 + kx];
    __bf16 hi = (__bf16)v;
    wsb[B2P_OFF + i] = p ? (__bf16)(v - (float)hi) : hi;
  } else if (i < 9216 + 36864) {
    int q = i - 9216;
    int f = q >> 9, r = q & 511;
    int l = r >> 3, j = r & 7;
    int t = f >> 3, nt = (f >> 1) & 3, p = f & 1;
    int ky = t / 3, kx = t % 3;
    int oc = nt * 16 + (l & 15), ic = ((l >> 4) << 3) + j;
    float v = w3[oc * 288 + ic * 9 + ky * 3 + kx];
    __bf16 hi = (__bf16)v;
    wsb[B3P_OFF + q] = p ? (__bf16)(v - (float)hi) : hi;
  } else if (i < 9216 + 36864 + 1024) {
    int q = i - (9216 + 36864);
    int f = q >> 9, r = q & 511;
    int l = r >> 3, j = r & 7;
    int oc = l & 15, k = ((l >> 4) << 3) + j;
    float v = 0.f;
    if (k < 27) {
      int kx = k / 9, rem = k % 9;
      int ky = rem / 3, ic = rem % 3;
      v = w1[oc * 27 + ic * 9 + ky * 3 + kx];
    }
    __bf16 hi = (__bf16)v;
    wsb[C1P_OFF + q] = f ? (__bf16)(v - (float)hi) : hi;
  }
}

// -------------------------------------------------------------- fused CNN
// 1 image/block, 4 waves. LDS union (16128 B -> 8 blocks/CU):
//   phase1: s_img @0 (9248B; cell = 4 ush [ic0,ic1,ic2,0])
//   phase2: s2 @0 (18 rows x 448 ush = 16128B; cell 24 ush, hi only)
//   phase3: s3 @0 (10 rows x 448 ush = 8960B; cell 40 ush, hi only)
//           h3s @8960 (4096B f32 [oc][py][px])
__global__ __launch_bounds__(256, 8) void cnn_fused(
    const float* __restrict__ x, const __bf16* __restrict__ wsb,
    const float* __restrict__ b1, const float* __restrict__ b2,
    const float* __restrict__ b3,
    const float* __restrict__ fcw, const float* __restrict__ fcb,
    float* __restrict__ out) {
  __shared__ __align__(16) unsigned char smem[16128];
  __bf16* s_img = (__bf16*)smem;
  __bf16* s2b   = (__bf16*)smem;
  __bf16* s3b   = (__bf16*)smem;
  float*  h3s   = (float*)(smem + 8960);

  const __bf16* b2p = wsb + B2P_OFF;
  const __bf16* b3p = wsb + B3P_OFF;
  const __bf16* c1p = wsb + C1P_OFF;

  const int tid = threadIdx.x;
  const int img = blockIdx.x;
  const int w = tid >> 6, lane = tid & 63;

  // ---- phase 1: zero s_img halo (132 cells) + write interior (disjoint)
  if (tid < 132) {
    int row, col;
    if (tid < 34)       { row = 0;        col = tid; }
    else if (tid < 68)  { row = 33;       col = tid - 34; }
    else if (tid < 100) { row = tid - 67; col = 0; }
    else                { row = tid - 99; col = 33; }
    *(unsigned long long*)&s_img[(row * 34 + col) * 4] = 0ull;
  }
  const float* xg = x + img * 3072;
  for (int i = tid; i < 1024; i += 256) {
    const int y = i >> 5, xx = i & 31;
    bf16x4 pk;
    pk.x = (__bf16)xg[i];
    pk.y = (__bf16)xg[i + 1024];
    pk.z = (__bf16)xg[i + 2048];
    pk.w = (__bf16)0.f;
    *(bf16x4*)&s_img[((y + 1) * 34 + (xx + 1)) * 4] = pk;
  }
  const bf16x8 B1h = *(const bf16x8*)(c1p + lane * 8);
  const bf16x8 B1l = *(const bf16x8*)(c1p + 512 + lane * 8);
  __syncthreads();

  // ---- conv1: K=27-in-32 packed MFMA. Lane kg=lane>>4 holds k = kg*8+j,
  // k = kx*9 + ky*3 + ic. A built from 6 ds_read_b64 + selects.
  float pooled[16];
  {
    const int xm = lane & 15, kg = lane >> 4;
    #pragma unroll
    for (int p = 0; p < 4; ++p) {
      f32x4 acc[2][2];
      #pragma unroll
      for (int ys = 0; ys < 2; ++ys)
        #pragma unroll
        for (int xh = 0; xh < 2; ++xh)
          #pragma unroll
          for (int r = 0; r < 4; ++r) acc[ys][xh][r] = 0.f;
      #pragma unroll
      for (int ys = 0; ys < 2; ++ys) {
        const int yqg = w * 8 + p * 2 + ys;
        #pragma unroll
        for (int xh = 0; xh < 2; ++xh) {
          const int xv = xh * 16 + xm;
          const int ca = xv + (kg <= 1 ? 0 : kg - 1);
          const int cb = xv + (kg < 2 ? 1 : 2);
          const uint2 qa0 = *(const uint2*)&s_img[((yqg + 0) * 34 + ca) * 4];
          const uint2 qa1 = *(const uint2*)&s_img[((yqg + 1) * 34 + ca) * 4];
          const uint2 qa2 = *(const uint2*)&s_img[((yqg + 2) * 34 + ca) * 4];
          const uint2 qb0 = *(const uint2*)&s_img[((yqg + 0) * 34 + cb) * 4];
          const uint2 qb1 = *(const uint2*)&s_img[((yqg + 1) * 34 + cb) * 4];
          const uint2 qb2 = *(const uint2*)&s_img[((yqg + 2) * 34 + cb) * 4];
          const uint a0 = qa0.x, a1 = qa0.y, a2 = qa1.x, a3 = qa1.y, a4 = qa2.x, a5 = qa2.y;
          const uint b0 = qb0.x, b1 = qb0.y, b2 = qb1.x, b3 = qb1.y, b4 = qb2.x;
          U4B8 A;
          A.u.x = kg == 0 ? a0
                : kg == 1 ? (a5 | (b0 << 16))
                : kg == 2 ? ((a4 >> 16) | (a5 << 16))
                :           a4;
          A.u.y = kg == 0 ? (a1 | (a2 << 16))
                : kg == 1 ? ((b0 >> 16) | (b1 << 16))
                : kg == 2 ? b0
                :           a5;
          A.u.z = kg == 0 ? ((a2 >> 16) | (a3 << 16))
                : kg == 1 ? b2
                : kg == 2 ? (b1 | (b2 << 16))
                :           0u;
          A.u.w = kg == 0 ? a4
                : kg == 1 ? (b3 | (b4 << 16))
                : kg == 2 ? ((b2 >> 16) | (b3 << 16))
                :           0u;
          acc[ys][xh] = __builtin_amdgcn_mfma_f32_16x16x32_bf16(A.b, B1h, acc[ys][xh], 0, 0, 0);
          acc[ys][xh] = __builtin_amdgcn_mfma_f32_16x16x32_bf16(A.b, B1l, acc[ys][xh], 0, 0, 0);
        }
      }
      #pragma unroll
      for (int xh = 0; xh < 2; ++xh)
        #pragma unroll
        for (int xp2 = 0; xp2 < 2; ++xp2) {
          const float v0 = fmaxf(acc[0][xh][xp2 * 2], acc[0][xh][xp2 * 2 + 1]);
          const float v1 = fmaxf(acc[1][xh][xp2 * 2], acc[1][xh][xp2 * 2 + 1]);
          pooled[p * 4 + xh * 2 + xp2] = fmaxf(v0, v1);
        }
    }
  }
  __syncthreads();   // s_img dead

  // ---- h1 (bias+relu, bf16 hi only) -> s2 (row stride 448, cell 24)
  if (tid < 68) {
    int row, col;
    if (tid < 18)      { row = 0;       col = tid; }
    else if (tid < 36) { row = 17;      col = tid - 18; }
    else if (tid < 52) { row = tid - 35; col = 0; }
    else               { row = tid - 51; col = 17; }
    unsigned long long* p = (unsigned long long*)&s2b[row * 448 + col * 24];
    p[0] = 0ull; p[1] = 0ull; p[2] = 0ull; p[3] = 0ull;
  }
  {
    const int oc = lane & 15, quad = lane >> 4;
    const float bias = b1[oc];
    #pragma unroll
    for (int p = 0; p < 4; ++p)
      #pragma unroll
      for (int xh = 0; xh < 2; ++xh)
        #pragma unroll
        for (int xp2 = 0; xp2 < 2; ++xp2) {
          const float v = fmaxf(pooled[p * 4 + xh * 2 + xp2] + bias, 0.f);
          const int py = w * 4 + p, px = xh * 8 + quad * 2 + xp2;
          s2b[(py + 1) * 448 + (px + 1) * 24 + oc] = (__bf16)v;
        }
  }
  bf16x8 Bf[18];
  #pragma unroll
  for (int f = 0; f < 18; ++f)
    Bf[f] = *(const bf16x8*)(b2p + f * 512 + lane * 8);
  __syncthreads();

  // ---- conv2 (2-term: a_h*(B_h+B_l)), stride-448 addressing
  float pooled2[8];
  {
    const unsigned short* s2 = (const unsigned short*)s2b;
    const int xm = lane & 15, yoff = (lane >> 4) & 1, kh = lane >> 5;
    f32x16v acc0, acc1;
    #pragma unroll
    for (int r = 0; r < 16; ++r) { acc0[r] = 0.f; acc1[r] = 0.f; }
    #pragma unroll
    for (int t = 0; t < 9; ++t) {
      const int ky = t / 3, kx = t % 3;
      const int col = (xm + kx) * 24 + kh * 8;
      const int row0 = (4 * w + yoff + ky) * 448 + col;
      const int row1 = row0 + 896;
      bf16x8 a0h = *(const bf16x8*)&s2[row0];
      bf16x8 a1h = *(const bf16x8*)&s2[row1];
      acc0 = __builtin_amdgcn_mfma_f32_32x32x16_bf16(a0h, Bf[t * 2],     acc0, 0, 0, 0);
      acc1 = __builtin_amdgcn_mfma_f32_32x32x16_bf16(a1h, Bf[t * 2],     acc1, 0, 0, 0);
      acc0 = __builtin_amdgcn_mfma_f32_32x32x16_bf16(a0h, Bf[t * 2 + 1], acc0, 0, 0, 0);
      acc1 = __builtin_amdgcn_mfma_f32_32x32x16_bf16(a1h, Bf[t * 2 + 1], acc1, 0, 0, 0);
    }
    #pragma unroll
    for (int i2 = 0; i2 < 2; ++i2) {
      const f32x16v& a = i2 ? acc1 : acc0;
      #pragma unroll
      for (int bq = 0; bq < 2; ++bq)
        #pragma unroll
        for (int rq = 0; rq < 2; ++rq) {
          const int r0 = bq * 4 + rq * 2;
          pooled2[i2 * 4 + bq * 2 + rq] =
              fmaxf(fmaxf(a[r0], a[r0 + 1]), fmaxf(a[r0 + 8], a[r0 + 9]));
        }
    }
  }
  __syncthreads();   // s2 dead

  // ---- h2 (bias+relu, bf16 hi only) -> s3 (row stride 448, cell 40)
  if (tid < 36) {
    int row, col;
    if (tid < 10)      { row = 0;       col = tid; }
    else if (tid < 20) { row = 9;       col = tid - 10; }
    else if (tid < 28) { row = tid - 19; col = 0; }
    else               { row = tid - 27; col = 9; }
    unsigned long long* p = (unsigned long long*)&s3b[row * 448 + col * 40];
    #pragma unroll
    for (int u = 0; u < 8; ++u) p[u] = 0ull;
  }
  {
    const int oc = lane & 31, hh = lane >> 5;
    const float bias = b2[oc];
    #pragma unroll
    for (int i2 = 0; i2 < 2; ++i2)
      #pragma unroll
      for (int bq = 0; bq < 2; ++bq)
        #pragma unroll
        for (int rq = 0; rq < 2; ++rq) {
          const float v = fmaxf(pooled2[i2 * 4 + bq * 2 + rq] + bias, 0.f);
          const int py = 2 * w + i2, px = 2 * hh + 4 * bq + rq;
          s3b[(py + 1) * 448 + (px + 1) * 40 + oc] = (__bf16)v;
        }
  }
  __syncthreads();

  // ---- conv3 (wave = nt = oc-tile), 2-term
  {
    const unsigned short* s3 = (const unsigned short*)s3b;
    const int nt = w;
    bf16x8 Bt[18];
    #pragma unroll
    for (int t = 0; t < 9; ++t) {
      Bt[t * 2]     = *(const bf16x8*)(b3p + (t * 8 + nt * 2) * 512 + lane * 8);
      Bt[t * 2 + 1] = *(const bf16x8*)(b3p + (t * 8 + nt * 2 + 1) * 512 + lane * 8);
    }
    const int m = lane & 15, quad = lane >> 4;
    const int xm = m & 7, yoff = m >> 3;
    f32x4 acc[4];
    #pragma unroll
    for (int mt = 0; mt < 4; ++mt)
      #pragma unroll
      for (int r = 0; r < 4; ++r) acc[mt][r] = 0.f;
    #pragma unroll
    for (int t = 0; t < 9; ++t) {
      const int ky = t / 3, kx = t % 3;
      #pragma unroll
      for (int mt = 0; mt < 4; ++mt) {
        const int ro = (2 * mt + yoff + ky) * 448 + (xm + kx) * 40 + quad * 8;
        bf16x8 ah = *(const bf16x8*)&s3[ro];
        acc[mt] = __builtin_amdgcn_mfma_f32_16x16x32_bf16(ah, Bt[t * 2],     acc[mt], 0, 0, 0);
        acc[mt] = __builtin_amdgcn_mfma_f32_16x16x32_bf16(ah, Bt[t * 2 + 1], acc[mt], 0, 0, 0);
      }
    }
    // epilogue -> h3s (disjoint from s3's read region)
    const int ocl = lane & 15;
    #pragma unroll
    for (int mt = 0; mt < 4; ++mt) {
      float p0 = fmaxf(acc[mt][0], acc[mt][1]);
      float p1 = fmaxf(acc[mt][2], acc[mt][3]);
      p0 = fmaxf(p0, __shfl_xor(p0, 32, 64));
      p1 = fmaxf(p1, __shfl_xor(p1, 32, 64));
      if (quad < 2) {
        const int oc = nt * 16 + ocl;
        const float bias = b3[oc];
        const int base = oc * 16 + mt * 4 + (quad & 1) * 2;
        h3s[base]     = fmaxf(p0 + bias, 0.f);
        h3s[base + 1] = fmaxf(p1 + bias, 0.f);
      }
    }
  }
  __syncthreads();

  // ---- fc (wave 0)
  if (w == 0) {
    float hv[16];
    #pragma unroll
    for (int i = 0; i < 16; ++i) hv[i] = h3s[i * 64 + lane];
    #pragma unroll
    for (int j = 0; j < 10; ++j) {
      float dot = 0.f;
      #pragma unroll
      for (int i = 0; i < 16; ++i)
        dot = fmaf(hv[i], fcw[j * 1024 + i * 64 + lane], dot);
      #pragma unroll
      for (int s = 32; s > 0; s >>= 1) dot += __shfl_xor(dot, s, 64);
      if (lane == 0) out[img * 10 + j] = dot + fcb[j];
    }
  }
}

// -------------------------------------------------------------------- launch
extern "C" void kernel_launch(void* const* d_in, const int* in_sizes, int n_in,
                              void* d_out, int out_size, void* d_ws, size_t ws_size,
                              hipStream_t stream) {
  const float* x   = (const float*)d_in[0];
  const float* w1  = (const float*)d_in[1];
  const float* b1  = (const float*)d_in[2];
  const float* w2  = (const float*)d_in[3];
  const float* b2  = (const float*)d_in[4];
  const float* w3  = (const float*)d_in[5];
  const float* b3  = (const float*)d_in[6];
  const float* fcw = (const float*)d_in[7];
  const float* fcb = (const float*)d_in[8];
  __bf16* wsb = (__bf16*)d_ws;
  float* out = (float*)d_out;

  hipLaunchKernelGGL(pack_weights, dim3(184), dim3(256), 0, stream, w1, w2, w3, wsb);
  hipLaunchKernelGGL(cnn_fused, dim3(4096), dim3(256), 0, stream,
                     x, wsb, b1, b2, b3, fcw, fcb, out);
}

// Round 10
// 155.774 us; speedup vs baseline: 1.7834x; 1.7834x over previous
//
#include <hip/hip_runtime.h>

typedef float f32x4 __attribute__((ext_vector_type(4)));
typedef float f32x16v __attribute__((ext_vector_type(16)));
typedef __bf16 bf16x4 __attribute__((ext_vector_type(4)));
typedef __bf16 bf16x8 __attribute__((ext_vector_type(8)));

union U4B8 { uint4 u; bf16x8 b; };

// ws layout (bf16 elements): b2p[9216] @0, b3p[36864] @9216, c1p[1024] @46080
#define B2P_OFF 0
#define B3P_OFF 9216
#define C1P_OFF 46080

// ------------------------------------------------------------- pack_weights
// b2p frag f=t*2+p: lane l, j: oc=l&31, ic=(l>>5)*8+j              (32x32x16)
// b3p frag f=t*8+nt*2+p: lane l, j: oc=nt*16+(l&15), ic=(l>>4)*8+j (16x16x32)
// c1p frag f in {Bh,Bl}: oc=l&15, k=(l>>4)*8+j, k = kx*9+ky*3+ic (<27), else 0
__global__ __launch_bounds__(256) void pack_weights(
    const float* __restrict__ w1, const float* __restrict__ w2,
    const float* __restrict__ w3, __bf16* __restrict__ wsb) {
  int i = blockIdx.x * 256 + threadIdx.x;
  if (i < 9216) {
    int f = i >> 9, r = i & 511;
    int l = r >> 3, j = r & 7;
    int t = f >> 1, p = f & 1;
    int ky = t / 3, kx = t % 3;
    int oc = l & 31, ic = ((l >> 5) << 3) + j;
    float v = w2[oc * 144 + ic * 9 + ky * 3 + kx];
    __bf16 hi = (__bf16)v;
    wsb[B2P_OFF + i] = p ? (__bf16)(v - (float)hi) : hi;
  } else if (i < 9216 + 36864) {
    int q = i - 9216;
    int f = q >> 9, r = q & 511;
    int l = r >> 3, j = r & 7;
    int t = f >> 3, nt = (f >> 1) & 3, p = f & 1;
    int ky = t / 3, kx = t % 3;
    int oc = nt * 16 + (l & 15), ic = ((l >> 4) << 3) + j;
    float v = w3[oc * 288 + ic * 9 + ky * 3 + kx];
    __bf16 hi = (__bf16)v;
    wsb[B3P_OFF + q] = p ? (__bf16)(v - (float)hi) : hi;
  } else if (i < 9216 + 36864 + 1024) {
    int q = i - (9216 + 36864);
    int f = q >> 9, r = q & 511;
    int l = r >> 3, j = r & 7;
    int oc = l & 15, k = ((l >> 4) << 3) + j;
    float v = 0.f;
    if (k < 27) {
      int kx = k / 9, rem = k % 9;
      int ky = rem / 3, ic = rem % 3;
      v = w1[oc * 27 + ic * 9 + ky * 3 + kx];
    }
    __bf16 hi = (__bf16)v;
    wsb[C1P_OFF + q] = f ? (__bf16)(v - (float)hi) : hi;
  }
}

// -------------------------------------------------------------- fused CNN
// 1 image/block, 4 waves. LDS union (16128 B):
//   phase1: s_img @0 (9248B; cell = 4 ush [ic0,ic1,ic2,0])
//   phase2: s2 @0 (18 rows x 448 ush = 16128B; cell 24 ush, hi only)
//   phase3: s3 @0 (10 rows x 448 ush = 8960B; cell 40 ush, hi only)
//           h3s @8960 (4096B f32 [oc][py][px])
// launch_bounds (256,4): VGPR cap 128 — (256,8) forced a 64-VGPR cap and
// catastrophic scratch spill in R9 (WRITE_SIZE 433 MB). Occupancy is then
// VGPR-limited at ~6-8 blocks/CU, LDS allows 9.
__global__ __launch_bounds__(256, 4) void cnn_fused(
    const float* __restrict__ x, const __bf16* __restrict__ wsb,
    const float* __restrict__ b1, const float* __restrict__ b2,
    const float* __restrict__ b3,
    const float* __restrict__ fcw, const float* __restrict__ fcb,
    float* __restrict__ out) {
  __shared__ __align__(16) unsigned char smem[16128];
  __bf16* s_img = (__bf16*)smem;
  __bf16* s2b   = (__bf16*)smem;
  __bf16* s3b   = (__bf16*)smem;
  float*  h3s   = (float*)(smem + 8960);

  const __bf16* b2p = wsb + B2P_OFF;
  const __bf16* b3p = wsb + B3P_OFF;
  const __bf16* c1p = wsb + C1P_OFF;

  const int tid = threadIdx.x;
  const int img = blockIdx.x;
  const int w = tid >> 6, lane = tid & 63;

  // ---- phase 1: zero s_img halo (132 cells) + write interior (disjoint)
  if (tid < 132) {
    int row, col;
    if (tid < 34)       { row = 0;        col = tid; }
    else if (tid < 68)  { row = 33;       col = tid - 34; }
    else if (tid < 100) { row = tid - 67; col = 0; }
    else                { row = tid - 99; col = 33; }
    *(unsigned long long*)&s_img[(row * 34 + col) * 4] = 0ull;
  }
  const float* xg = x + img * 3072;
  for (int i = tid; i < 1024; i += 256) {
    const int y = i >> 5, xx = i & 31;
    bf16x4 pk;
    pk.x = (__bf16)xg[i];
    pk.y = (__bf16)xg[i + 1024];
    pk.z = (__bf16)xg[i + 2048];
    pk.w = (__bf16)0.f;
    *(bf16x4*)&s_img[((y + 1) * 34 + (xx + 1)) * 4] = pk;
  }
  const bf16x8 B1h = *(const bf16x8*)(c1p + lane * 8);
  const bf16x8 B1l = *(const bf16x8*)(c1p + 512 + lane * 8);
  __syncthreads();

  // ---- conv1: K=27-in-32 packed MFMA. Lane kg=lane>>4 holds k = kg*8+j,
  // k = kx*9 + ky*3 + ic. A built from 6 ds_read_b64 + selects.
  float pooled[16];
  {
    const int xm = lane & 15, kg = lane >> 4;
    #pragma unroll
    for (int p = 0; p < 4; ++p) {
      f32x4 acc[2][2];
      #pragma unroll
      for (int ys = 0; ys < 2; ++ys)
        #pragma unroll
        for (int xh = 0; xh < 2; ++xh)
          #pragma unroll
          for (int r = 0; r < 4; ++r) acc[ys][xh][r] = 0.f;
      #pragma unroll
      for (int ys = 0; ys < 2; ++ys) {
        const int yqg = w * 8 + p * 2 + ys;
        #pragma unroll
        for (int xh = 0; xh < 2; ++xh) {
          const int xv = xh * 16 + xm;
          const int ca = xv + (kg <= 1 ? 0 : kg - 1);
          const int cb = xv + (kg < 2 ? 1 : 2);
          const uint2 qa0 = *(const uint2*)&s_img[((yqg + 0) * 34 + ca) * 4];
          const uint2 qa1 = *(const uint2*)&s_img[((yqg + 1) * 34 + ca) * 4];
          const uint2 qa2 = *(const uint2*)&s_img[((yqg + 2) * 34 + ca) * 4];
          const uint2 qb0 = *(const uint2*)&s_img[((yqg + 0) * 34 + cb) * 4];
          const uint2 qb1 = *(const uint2*)&s_img[((yqg + 1) * 34 + cb) * 4];
          const uint2 qb2 = *(const uint2*)&s_img[((yqg + 2) * 34 + cb) * 4];
          const uint a0 = qa0.x, a1 = qa0.y, a2 = qa1.x, a3 = qa1.y, a4 = qa2.x, a5 = qa2.y;
          const uint b0 = qb0.x, b1 = qb0.y, b2 = qb1.x, b3 = qb1.y, b4 = qb2.x;
          U4B8 A;
          A.u.x = kg == 0 ? a0
                : kg == 1 ? (a5 | (b0 << 16))
                : kg == 2 ? ((a4 >> 16) | (a5 << 16))
                :           a4;
          A.u.y = kg == 0 ? (a1 | (a2 << 16))
                : kg == 1 ? ((b0 >> 16) | (b1 << 16))
                : kg == 2 ? b0
                :           a5;
          A.u.z = kg == 0 ? ((a2 >> 16) | (a3 << 16))
                : kg == 1 ? b2
                : kg == 2 ? (b1 | (b2 << 16))
                :           0u;
          A.u.w = kg == 0 ? a4
                : kg == 1 ? (b3 | (b4 << 16))
                : kg == 2 ? ((b2 >> 16) | (b3 << 16))
                :           0u;
          acc[ys][xh] = __builtin_amdgcn_mfma_f32_16x16x32_bf16(A.b, B1h, acc[ys][xh], 0, 0, 0);
          acc[ys][xh] = __builtin_amdgcn_mfma_f32_16x16x32_bf16(A.b, B1l, acc[ys][xh], 0, 0, 0);
        }
      }
      #pragma unroll
      for (int xh = 0; xh < 2; ++xh)
        #pragma unroll
        for (int xp2 = 0; xp2 < 2; ++xp2) {
          const float v0 = fmaxf(acc[0][xh][xp2 * 2], acc[0][xh][xp2 * 2 + 1]);
          const float v1 = fmaxf(acc[1][xh][xp2 * 2], acc[1][xh][xp2 * 2 + 1]);
          pooled[p * 4 + xh * 2 + xp2] = fmaxf(v0, v1);
        }
    }
  }
  __syncthreads();   // s_img dead

  // ---- h1 (bias+relu, bf16 hi only) -> s2 (row stride 448, cell 24)
  if (tid < 68) {
    int row, col;
    if (tid < 18)      { row = 0;       col = tid; }
    else if (tid < 36) { row = 17;      col = tid - 18; }
    else if (tid < 52) { row = tid - 35; col = 0; }
    else               { row = tid - 51; col = 17; }
    unsigned long long* p = (unsigned long long*)&s2b[row * 448 + col * 24];
    p[0] = 0ull; p[1] = 0ull; p[2] = 0ull; p[3] = 0ull;
  }
  {
    const int oc = lane & 15, quad = lane >> 4;
    const float bias = b1[oc];
    #pragma unroll
    for (int p = 0; p < 4; ++p)
      #pragma unroll
      for (int xh = 0; xh < 2; ++xh)
        #pragma unroll
        for (int xp2 = 0; xp2 < 2; ++xp2) {
          const float v = fmaxf(pooled[p * 4 + xh * 2 + xp2] + bias, 0.f);
          const int py = w * 4 + p, px = xh * 8 + quad * 2 + xp2;
          s2b[(py + 1) * 448 + (px + 1) * 24 + oc] = (__bf16)v;
        }
  }
  bf16x8 Bf[18];
  #pragma unroll
  for (int f = 0; f < 18; ++f)
    Bf[f] = *(const bf16x8*)(b2p + f * 512 + lane * 8);
  __syncthreads();

  // ---- conv2 (2-term: a_h*(B_h+B_l)), stride-448 addressing
  float pooled2[8];
  {
    const unsigned short* s2 = (const unsigned short*)s2b;
    const int xm = lane & 15, yoff = (lane >> 4) & 1, kh = lane >> 5;
    f32x16v acc0, acc1;
    #pragma unroll
    for (int r = 0; r < 16; ++r) { acc0[r] = 0.f; acc1[r] = 0.f; }
    #pragma unroll
    for (int t = 0; t < 9; ++t) {
      const int ky = t / 3, kx = t % 3;
      const int col = (xm + kx) * 24 + kh * 8;
      const int row0 = (4 * w + yoff + ky) * 448 + col;
      const int row1 = row0 + 896;
      bf16x8 a0h = *(const bf16x8*)&s2[row0];
      bf16x8 a1h = *(const bf16x8*)&s2[row1];
      acc0 = __builtin_amdgcn_mfma_f32_32x32x16_bf16(a0h, Bf[t * 2],     acc0, 0, 0, 0);
      acc1 = __builtin_amdgcn_mfma_f32_32x32x16_bf16(a1h, Bf[t * 2],     acc1, 0, 0, 0);
      acc0 = __builtin_amdgcn_mfma_f32_32x32x16_bf16(a0h, Bf[t * 2 + 1], acc0, 0, 0, 0);
      acc1 = __builtin_amdgcn_mfma_f32_32x32x16_bf16(a1h, Bf[t * 2 + 1], acc1, 0, 0, 0);
    }
    #pragma unroll
    for (int i2 = 0; i2 < 2; ++i2) {
      const f32x16v& a = i2 ? acc1 : acc0;
      #pragma unroll
      for (int bq = 0; bq < 2; ++bq)
        #pragma unroll
        for (int rq = 0; rq < 2; ++rq) {
          const int r0 = bq * 4 + rq * 2;
          pooled2[i2 * 4 + bq * 2 + rq] =
              fmaxf(fmaxf(a[r0], a[r0 + 1]), fmaxf(a[r0 + 8], a[r0 + 9]));
        }
    }
  }
  __syncthreads();   // s2 dead

  // ---- h2 (bias+relu, bf16 hi only) -> s3 (row stride 448, cell 40)
  if (tid < 36) {
    int row, col;
    if (tid < 10)      { row = 0;       col = tid; }
    else if (tid < 20) { row = 9;       col = tid - 10; }
    else if (tid < 28) { row = tid - 19; col = 0; }
    else               { row = tid - 27; col = 9; }
    unsigned long long* p = (unsigned long long*)&s3b[row * 448 + col * 40];
    #pragma unroll
    for (int u = 0; u < 8; ++u) p[u] = 0ull;
  }
  {
    const int oc = lane & 31, hh = lane >> 5;
    const float bias = b2[oc];
    #pragma unroll
    for (int i2 = 0; i2 < 2; ++i2)
      #pragma unroll
      for (int bq = 0; bq < 2; ++bq)
        #pragma unroll
        for (int rq = 0; rq < 2; ++rq) {
          const float v = fmaxf(pooled2[i2 * 4 + bq * 2 + rq] + bias, 0.f);
          const int py = 2 * w + i2, px = 2 * hh + 4 * bq + rq;
          s3b[(py + 1) * 448 + (px + 1) * 40 + oc] = (__bf16)v;
        }
  }
  __syncthreads();

  // ---- conv3 (wave = nt = oc-tile), 2-term
  {
    const unsigned short* s3 = (const unsigned short*)s3b;
    const int nt = w;
    bf16x8 Bt[18];
    #pragma unroll
    for (int t = 0; t < 9; ++t) {
      Bt[t * 2]     = *(const bf16x8*)(b3p + (t * 8 + nt * 2) * 512 + lane * 8);
      Bt[t * 2 + 1] = *(const bf16x8*)(b3p + (t * 8 + nt * 2 + 1) * 512 + lane * 8);
    }
    const int m = lane & 15, quad = lane >> 4;
    const int xm = m & 7, yoff = m >> 3;
    f32x4 acc[4];
    #pragma unroll
    for (int mt = 0; mt < 4; ++mt)
      #pragma unroll
      for (int r = 0; r < 4; ++r) acc[mt][r] = 0.f;
    #pragma unroll
    for (int t = 0; t < 9; ++t) {
      const int ky = t / 3, kx = t % 3;
      #pragma unroll
      for (int mt = 0; mt < 4; ++mt) {
        const int ro = (2 * mt + yoff + ky) * 448 + (xm + kx) * 40 + quad * 8;
        bf16x8 ah = *(const bf16x8*)&s3[ro];
        acc[mt] = __builtin_amdgcn_mfma_f32_16x16x32_bf16(ah, Bt[t * 2],     acc[mt], 0, 0, 0);
        acc[mt] = __builtin_amdgcn_mfma_f32_16x16x32_bf16(ah, Bt[t * 2 + 1], acc[mt], 0, 0, 0);
      }
    }
    // epilogue -> h3s (disjoint from s3's read region)
    const int ocl = lane & 15;
    #pragma unroll
    for (int mt = 0; mt < 4; ++mt) {
      float p0 = fmaxf(acc[mt][0], acc[mt][1]);
      float p1 = fmaxf(acc[mt][2], acc[mt][3]);
      p0 = fmaxf(p0, __shfl_xor(p0, 32, 64));
      p1 = fmaxf(p1, __shfl_xor(p1, 32, 64));
      if (quad < 2) {
        const int oc = nt * 16 + ocl;
        const float bias = b3[oc];
        const int base = oc * 16 + mt * 4 + (quad & 1) * 2;
        h3s[base]     = fmaxf(p0 + bias, 0.f);
        h3s[base + 1] = fmaxf(p1 + bias, 0.f);
      }
    }
  }
  __syncthreads();

  // ---- fc (wave 0)
  if (w == 0) {
    float hv[16];
    #pragma unroll
    for (int i = 0; i < 16; ++i) hv[i] = h3s[i * 64 + lane];
    #pragma unroll
    for (int j = 0; j < 10; ++j) {
      float dot = 0.f;
      #pragma unroll
      for (int i = 0; i < 16; ++i)
        dot = fmaf(hv[i], fcw[j * 1024 + i * 64 + lane], dot);
      #pragma unroll
      for (int s = 32; s > 0; s >>= 1) dot += __shfl_xor(dot, s, 64);
      if (lane == 0) out[img * 10 + j] = dot + fcb[j];
    }
  }
}

// -------------------------------------------------------------------- launch
extern "C" void kernel_launch(void* const* d_in, const int* in_sizes, int n_in,
                              void* d_out, int out_size, void* d_ws, size_t ws_size,
                              hipStream_t stream) {
  const float* x   = (const float*)d_in[0];
  const float* w1  = (const float*)d_in[1];
  const float* b1  = (const float*)d_in[2];
  const float* w2  = (const float*)d_in[3];
  const float* b2  = (const float*)d_in[4];
  const float* w3  = (const float*)d_in[5];
  const float* b3  = (const float*)d_in[6];
  const float* fcw = (const float*)d_in[7];
  const float* fcb = (const float*)d_in[8];
  __bf16* wsb = (__bf16*)d_ws;
  float* out = (float*)d_out;

  hipLaunchKernelGGL(pack_weights, dim3(184), dim3(256), 0, stream, w1, w2, w3, wsb);
  hipLaunchKernelGGL(cnn_fused, dim3(4096), dim3(256), 0, stream,
                     x, wsb, b1, b2, b3, fcw, fcb, out);
}